// Round 2
// baseline (958.718 us; speedup 1.0000x reference)
//
#include <hip/hip_runtime.h>
#include <hip/hip_bf16.h>
#include <stdint.h>

#define S_ 1024
#define B_ 8
#define E_ 1024
#define H_ 16

typedef __bf16 bf16;
typedef bf16 bf16x8 __attribute__((ext_vector_type(8)));
typedef float fx4 __attribute__((ext_vector_type(4)));
typedef uint32_t u32x2 __attribute__((ext_vector_type(2)));

// log2(e)/8 folded into Q weights+bias so logits are already in exp2 domain
#define QSCALE 0.18033688011112042f

static __device__ __forceinline__ fx4 mfma_bf16(bf16x8 a, bf16x8 b, fx4 c) {
  return __builtin_amdgcn_mfma_f32_16x16x32_bf16(a, b, c, 0, 0, 0);
}

static __device__ __forceinline__ void gload16(const void* g, void* lds) {
  __builtin_amdgcn_global_load_lds(
      (const __attribute__((address_space(1))) unsigned int*)g,
      (__attribute__((address_space(3))) unsigned int*)lds, 16, 0, 0);
}

static __device__ __forceinline__ uint32_t cvtpk(float lo, float hi) {
  uint32_t r;
  asm("v_cvt_pk_bf16_f32 %0, %1, %2" : "=v"(r) : "v"(lo), "v"(hi));
  return r;
}

// ---------------------------------------------------------------- cast f32->bf16 (+ optional scale on first limit8*8 elems)
__global__ __launch_bounds__(256) void k_cast(const float* __restrict__ src,
                                              bf16* __restrict__ dst, int n8,
                                              int limit8, float scale) {
  int i = blockIdx.x * 256 + threadIdx.x;
  if (i >= n8) return;
  const float sc = (i < limit8) ? scale : 1.0f;
  const fx4* s4 = (const fx4*)src;
  fx4 a = s4[2 * i], b = s4[2 * i + 1];
  bf16x8 o;
  o[0] = (bf16)(a[0] * sc); o[1] = (bf16)(a[1] * sc);
  o[2] = (bf16)(a[2] * sc); o[3] = (bf16)(a[3] * sc);
  o[4] = (bf16)(b[0] * sc); o[5] = (bf16)(b[1] * sc);
  o[6] = (bf16)(b[2] * sc); o[7] = (bf16)(b[3] * sc);
  ((bf16x8*)dst)[i] = o;
}

// ---------------------------------------------------------------- GEMM C[M,N] = A[M,K] * W[N,K]^T + bias
// 128x128 tile, BK=32, 4 waves. 1-D grid with XCD-chunk swizzle.
template <int MODE>
__global__ __launch_bounds__(256) void k_gemm(const bf16* __restrict__ A,
                                              const bf16* __restrict__ W,
                                              const float* __restrict__ bias, int K,
                                              bf16* __restrict__ Qg, bf16* __restrict__ Kg,
                                              bf16* __restrict__ Vt, float* __restrict__ Cout) {
  __shared__ __align__(16) bf16 As[128 * 32];
  __shared__ __align__(16) bf16 Bs[128 * 32];
  const int tid = threadIdx.x;
  const int l = tid & 63, w = tid >> 6;
  const int r16 = l & 15, kg = l >> 4;
  // XCD swizzle: xcd = bid&7 owns bx in [xcd*8, xcd*8+8), all by
  const int bid = (int)blockIdx.x;
  const int ii = bid >> 3;
  const int bx = (bid & 7) * 8 + (ii & 7);
  const int by = ii >> 3;
  const int row0 = bx * 128, col0 = by * 128;
  const int wm = (w >> 1) * 64, wn = (w & 1) * 64;

  fx4 acc[4][4];
#pragma unroll
  for (int i = 0; i < 4; i++)
#pragma unroll
    for (int j = 0; j < 4; j++) acc[i][j] = (fx4){0.f, 0.f, 0.f, 0.f};

  const int rA = w * 16 + (l >> 2);
  const int srcoff = (((l & 3) ^ ((rA >> 1) & 3)) * 8);
  const size_t gA0 = (size_t)(row0 + rA) * K + srcoff;
  const size_t gA1 = (size_t)(row0 + rA + 64) * K + srcoff;
  const size_t gB0 = (size_t)(col0 + rA) * K + srcoff;
  const size_t gB1 = (size_t)(col0 + rA + 64) * K + srcoff;
  char* ldsA = (char*)As + w * 1024;
  char* ldsB = (char*)Bs + w * 1024;

  for (int k0 = 0; k0 < K; k0 += 32) {
    gload16(A + gA0 + k0, ldsA);
    gload16(A + gA1 + k0, ldsA + 4096);
    gload16(W + gB0 + k0, ldsB);
    gload16(W + gB1 + k0, ldsB + 4096);
    __syncthreads();
    bf16x8 af[4], bfr[4];
#pragma unroll
    for (int i = 0; i < 4; i++) {
      int r = wm + i * 16 + r16;
      af[i] = *(const bf16x8*)((char*)As + r * 64 + ((kg ^ ((r >> 1) & 3)) * 16));
    }
#pragma unroll
    for (int j = 0; j < 4; j++) {
      int r = wn + j * 16 + r16;
      bfr[j] = *(const bf16x8*)((char*)Bs + r * 64 + ((kg ^ ((r >> 1) & 3)) * 16));
    }
    __builtin_amdgcn_s_setprio(1);
#pragma unroll
    for (int i = 0; i < 4; i++)
#pragma unroll
      for (int j = 0; j < 4; j++) acc[i][j] = mfma_bf16(af[i], bfr[j], acc[i][j]);
    __builtin_amdgcn_s_setprio(0);
    __syncthreads();
  }

#pragma unroll
  for (int j = 0; j < 4; j++) {
    const int cg = col0 + wn + j * 16 + r16;
    float bs = bias[cg];
    if (MODE == 0) {
      const int sec = cg >> 10;  // 0=q 1=k 2=v (uniform per block: 128-col blocks)
      if (sec == 0) bs *= QSCALE;
      const int e = cg & 1023;
      const int h = e >> 6, dh = e & 63;
#pragma unroll
      for (int i = 0; i < 4; i++) {
#pragma unroll
        for (int t = 0; t < 4; t++) {
          const int rg = row0 + wm + i * 16 + kg * 4 + t;
          const int s = rg >> 3, bb = rg & 7;
          const int head = bb * 16 + h;
          const float v = acc[i][j][t] + bs;
          if (sec == 0)
            Qg[((size_t)head * 1024 + s) * 64 + dh] = (bf16)v;
          else if (sec == 1)
            Kg[((size_t)head * 1024 + s) * 64 + dh] = (bf16)v;
          else
            Vt[((size_t)head * 64 + dh) * 1024 + s] = (bf16)v;
        }
      }
    } else {
#pragma unroll
      for (int i = 0; i < 4; i++)
#pragma unroll
        for (int t = 0; t < 4; t++) {
          const int rg = row0 + wm + i * 16 + kg * 4 + t;
          Cout[(size_t)rg * 1024 + cg] = acc[i][j][t] + bs;
        }
    }
  }
}

// ---------------------------------------------------------------- attention
// wg = (head, 16-query block). Swapped-operand QK^T: lane holds 4 consecutive
// keys for one query row -> packed b64 P writes + in-loop row-sum accumulation.
// P LDS: bf16 [16 q][1024 keys], byte = q*2048 + ((key*2) ^ ((q&7)<<4))
__global__ __launch_bounds__(256, 4) void k_attn(const bf16* __restrict__ Qg,
                                                 const bf16* __restrict__ Kg,
                                                 const bf16* __restrict__ Vt,
                                                 const int* __restrict__ mask,
                                                 float* __restrict__ attn_out,
                                                 bf16* __restrict__ o_mid) {
  __shared__ __align__(16) bf16 P[16 * 1024];
  __shared__ __align__(16) float mm[1024];
  __shared__ float psum[16][4];
  __shared__ float rinv[16];
  __shared__ int mrow[16];

  const int tid = threadIdx.x;
  const int l = tid & 63, w = tid >> 6;
  const int r16 = l & 15, kg = l >> 4;
  // XCD swizzle: each XCD owns 16 contiguous heads (8192 blocks, %8==0)
  const int bid = (int)blockIdx.x;
  const int lb = (bid & 7) * 1024 + (bid >> 3);
  const int head = lb >> 6;
  const int q0 = (lb & 63) << 4;
  const int b = head >> 4, h = head & 15;

  for (int i = tid; i < 1024; i += 256) mm[i] = mask[b * 1024 + i] ? 1.0f : 0.0f;
  if (tid < 16) mrow[tid] = mask[b * 1024 + q0 + tid];
  __syncthreads();

  // Q frag = B operand: n = query = r16, k = dh
  const bf16* qp = Qg + ((size_t)head * 1024 + q0 + r16) * 64 + kg * 8;
  const bf16x8 bq0 = *(const bf16x8*)qp;
  const bf16x8 bq1 = *(const bf16x8*)(qp + 32);

  const int xr = (r16 & 7) << 4;
  const int prow = r16 * 2048;
  float lsum = 0.f;

#pragma unroll 4
  for (int t = 0; t < 16; t++) {
    const int key0 = w * 256 + t * 16;
    const bf16* kp = Kg + ((size_t)head * 1024 + key0 + r16) * 64 + kg * 8;
    bf16x8 a0 = *(const bf16x8*)kp;
    bf16x8 a1 = *(const bf16x8*)(kp + 32);
    fx4 c = {0.f, 0.f, 0.f, 0.f};
    __builtin_amdgcn_s_setprio(1);
    c = mfma_bf16(a0, bq0, c);  // A=K (m=key), B=Q (n=query)
    c = mfma_bf16(a1, bq1, c);
    __builtin_amdgcn_s_setprio(0);
    const int k4 = key0 + kg * 4;
    const fx4 m4 = *(const fx4*)&mm[k4];
    const float p0 = exp2f(c[0]) * m4[0];
    const float p1 = exp2f(c[1]) * m4[1];
    const float p2 = exp2f(c[2]) * m4[2];
    const float p3 = exp2f(c[3]) * m4[3];
    lsum += (p0 + p1) + (p2 + p3);
    u32x2 pk;
    pk[0] = cvtpk(p0, p1);
    pk[1] = cvtpk(p2, p3);
    *(u32x2*)((char*)P + prow + ((k4 * 2) ^ xr)) = pk;
  }
  // reduce over kg groups (lanes r16, r16+16, r16+32, r16+48)
  lsum += __shfl_xor(lsum, 16, 64);
  lsum += __shfl_xor(lsum, 32, 64);
  if (l < 16) psum[l][w] = lsum;
  __syncthreads();

  // masked-query rows -> exact uniform 1/1024; compute rinv
  {
    const int r = tid >> 4, c16 = tid & 15;
    if (mrow[r] == 0) {
      bf16x8 f;
#pragma unroll
      for (int j = 0; j < 8; j++) f[j] = (bf16)0.0009765625f;
      const int xrr = (r & 7) << 4;
#pragma unroll
      for (int i = 0; i < 8; i++)
        *(bf16x8*)((char*)P + r * 2048 + ((c16 * 16 + i * 256) ^ xrr)) = f;
    }
  }
  if (tid < 16) {
    const float s = (psum[tid][0] + psum[tid][1]) + (psum[tid][2] + psum[tid][3]);
    rinv[tid] = mrow[tid] ? 1.0f / s : 1.0f;
  }
  __syncthreads();

  // attention-matrix write: 16 threads per row, b128 P reads, 512B runs
  {
    const int r = tid >> 4, c16 = tid & 15;
    const float ri = rinv[r];
    const int xrr = (r & 7) << 4;
    float* op = attn_out + ((size_t)head * 1024 + q0 + r) * 1024;
#pragma unroll
    for (int i = 0; i < 8; i++) {
      const int key = i * 128 + c16 * 8;
      bf16x8 pv = *(const bf16x8*)((char*)P + r * 2048 + ((key * 2) ^ xrr));
      fx4 o0, o1;
      o0[0] = (float)pv[0] * ri; o0[1] = (float)pv[1] * ri;
      o0[2] = (float)pv[2] * ri; o0[3] = (float)pv[3] * ri;
      o1[0] = (float)pv[4] * ri; o1[1] = (float)pv[5] * ri;
      o1[2] = (float)pv[6] * ri; o1[3] = (float)pv[7] * ri;
      *(fx4*)(op + key) = o0;
      *(fx4*)(op + key + 4) = o1;
    }
  }

  // PV (swapped): A = V^T rows (m=dh), B = P (n=query). Lane -> 4 consecutive dh.
  {
    fx4 c = {0.f, 0.f, 0.f, 0.f};
    const bf16* vp = Vt + ((size_t)head * 64 + w * 16 + r16) * 1024 + kg * 8;
#pragma unroll 4
    for (int kt = 0; kt < 32; kt++) {
      bf16x8 a = *(const bf16x8*)(vp + kt * 32);
      bf16x8 bp = *(const bf16x8*)((char*)P + r16 * 2048 + ((kt * 64 + kg * 16) ^ xr));
      __builtin_amdgcn_s_setprio(1);
      c = mfma_bf16(a, bp, c);
      __builtin_amdgcn_s_setprio(0);
    }
    const float ri = rinv[r16];
    u32x2 pk;
    pk[0] = cvtpk(c[0] * ri, c[1] * ri);
    pk[1] = cvtpk(c[2] * ri, c[3] * ri);
    // o_mid[(q0+r16)*8 + b][h*64 + w*16 + kg*4 .. +3]
    *(u32x2*)&o_mid[((size_t)(q0 + r16) * 8 + b) * 1024 + h * 64 + w * 16 + kg * 4] = pk;
  }
}

// ----------------------------------------------------------------
extern "C" void kernel_launch(void* const* d_in, const int* in_sizes, int n_in,
                              void* d_out, int out_size, void* d_ws, size_t ws_size,
                              hipStream_t stream) {
  const float* x = (const float*)d_in[0];
  const int* mask = (const int*)d_in[1];
  const float* qkv_w = (const float*)d_in[2];
  const float* qkv_b = (const float*)d_in[3];
  const float* out_w = (const float*)d_in[4];
  const float* out_b = (const float*)d_in[5];

  float* out_o = (float*)d_out;
  float* out_attn = out_o + (size_t)S_ * B_ * E_;

  char* ws = (char*)d_ws;
  bf16* x_bf = (bf16*)(ws);
  bf16* wqkv_bf = (bf16*)(ws + (16ull << 20));
  bf16* wout_bf = (bf16*)(ws + (22ull << 20));
  bf16* Qg = (bf16*)(ws + (24ull << 20));
  bf16* Kg = (bf16*)(ws + (40ull << 20));
  bf16* Vt = (bf16*)(ws + (56ull << 20));
  bf16* o_mid = (bf16*)(ws + (72ull << 20));

  k_cast<<<4096, 256, 0, stream>>>(x, x_bf, 1048576, 0, 1.0f);
  k_cast<<<1536, 256, 0, stream>>>(qkv_w, wqkv_bf, 393216, 131072, QSCALE);
  k_cast<<<512, 256, 0, stream>>>(out_w, wout_bf, 131072, 0, 1.0f);

  k_gemm<0><<<1536, 256, 0, stream>>>(x_bf, wqkv_bf, qkv_b, 1024, Qg, Kg, Vt, nullptr);

  k_attn<<<8192, 256, 0, stream>>>(Qg, Kg, Vt, mask, out_attn, o_mid);

  k_gemm<1><<<512, 256, 0, stream>>>(o_mid, wout_bf, out_b, 1024, nullptr, nullptr, nullptr, out_o);
}